// Round 1
// baseline (23229.091 us; speedup 1.0000x reference)
//
#include <hip/hip_runtime.h>
#include <math.h>

#define T_TRI 20000
#define KNN_K 20
#define H     128

// ---------------- workspace layout (bytes) ----------------
// geo : T*12 f32 (tmin3,tmax3,bary3,pad3) = 960000
// bq  : T*4  f32 (bary.xyz, sq)           = 320000
// nbr : T*20 i32                          = 1600000
// rs  : 128 f32
// X,Y,S : T*128 f32 each                  = 10.24MB each
#define WS_GEO   0
#define WS_BQ    (1u<<20)
#define WS_NBR   (2u<<20)
#define WS_RS    (4u<<20)
#define WS_X     (5u<<20)
#define WS_Y     (16u<<20)
#define WS_S     (27u<<20)
// total need ~38MB

// ---------------- geometry ----------------
__global__ void geom_kernel(const float* __restrict__ pts, const int* __restrict__ tris,
                            float* __restrict__ geo, float4* __restrict__ bq) {
    int t = blockIdx.x * blockDim.x + threadIdx.x;
    if (t >= T_TRI) return;
    int i0 = tris[3*t], i1 = tris[3*t+1], i2 = tris[3*t+2];
    float ax = pts[3*i0], ay = pts[3*i0+1], az = pts[3*i0+2];
    float bx = pts[3*i1], by = pts[3*i1+1], bz = pts[3*i1+2];
    float cx = pts[3*i2], cy = pts[3*i2+1], cz = pts[3*i2+2];
    float e0x = ax-bx, e0y = ay-by, e0z = az-bz;   // e_ij
    float e1x = ax-cx, e1y = ay-cy, e1z = az-cz;   // e_ik
    float e2x = bx-cx, e2y = by-cy, e2z = bz-cz;   // e_jk
    float mnx = fminf(fminf(e0x,e1x),e2x), mny = fminf(fminf(e0y,e1y),e2y), mnz = fminf(fminf(e0z,e1z),e2z);
    float mxx = fmaxf(fmaxf(e0x,e1x),e2x), mxy = fmaxf(fmaxf(e0y,e1y),e2y), mxz = fmaxf(fmaxf(e0z,e1z),e2z);
    float gx = (ax+bx+cx)*(1.0f/3.0f), gy = (ay+by+cy)*(1.0f/3.0f), gz = (az+bz+cz)*(1.0f/3.0f);
    float sq = (gx*gx + gy*gy) + gz*gz;
    float* g = geo + (size_t)t*12;
    g[0]=mnx; g[1]=mny; g[2]=mnz; g[3]=mxx; g[4]=mxy; g[5]=mxz;
    g[6]=gx;  g[7]=gy;  g[8]=gz;  g[9]=0.f; g[10]=0.f; g[11]=0.f;
    bq[t] = make_float4(gx, gy, gz, sq);
}

// ---------------- knn: 8 rows per block (8 waves), candidate tiles in LDS ----------------
#define KTILE 2048
__global__ __launch_bounds__(512) void knn_kernel(const float4* __restrict__ bq, int* __restrict__ nbr) {
    __shared__ float4 tile[KTILE];
    __shared__ float  md[8][64*21];
    __shared__ int    mi[8][64*21];
    int wave = threadIdx.x >> 6;
    int lane = threadIdx.x & 63;
    int row  = blockIdx.x * 8 + wave;
    float4 me = bq[row];
    float ad[21]; int ai[21];
#pragma unroll
    for (int p = 0; p < 21; ++p) { ad[p] = INFINITY; ai[p] = 0x7FFFFFFF; }

    for (int base = 0; base < T_TRI; base += KTILE) {
        int n = min(KTILE, T_TRI - base);
        __syncthreads();
        for (int k = threadIdx.x; k < n; k += 512) tile[k] = bq[base + k];
        __syncthreads();
        for (int k = lane; k < n; k += 64) {
            float4 c = tile[k];
            float dot = fmaf(me.z, c.z, fmaf(me.y, c.y, me.x*c.x));
            float d = (me.w + c.w) - 2.0f*dot;
            int j = base + k;
            if ((d < ad[20]) || (d == ad[20] && j < ai[20])) {
                ad[20] = d; ai[20] = j;
#pragma unroll
                for (int p = 20; p >= 1; --p) {
                    bool lt = (ad[p] < ad[p-1]) || (ad[p] == ad[p-1] && ai[p] < ai[p-1]);
                    float td = lt ? ad[p] : ad[p-1]; float tu = lt ? ad[p-1] : ad[p];
                    int   id = lt ? ai[p] : ai[p-1]; int   iu = lt ? ai[p-1] : ai[p];
                    ad[p-1] = td; ad[p] = tu; ai[p-1] = id; ai[p] = iu;
                }
            }
        }
    }
    // dump per-lane sorted lists, then 64-way merge (21 argmin rounds)
#pragma unroll
    for (int p = 0; p < 21; ++p) { md[wave][lane*21+p] = ad[p]; mi[wave][lane*21+p] = ai[p]; }
    __syncthreads();
    int ptr = 0;
    for (int r = 0; r < 21; ++r) {
        float cd = (ptr < 21) ? md[wave][lane*21+ptr] : INFINITY;
        int   ci = (ptr < 21) ? mi[wave][lane*21+ptr] : 0x7FFFFFFF;
        float wd = cd; int wi = ci;
#pragma unroll
        for (int off = 32; off >= 1; off >>= 1) {
            float od = __shfl_xor(wd, off);
            int   oi = __shfl_xor(wi, off);
            if ((od < wd) || (od == wd && oi < wi)) { wd = od; wi = oi; }
        }
        if (r > 0 && lane == 0) nbr[row*KNN_K + (r-1)] = wi;
        if (cd == wd && ci == wi) ptr++;
    }
}

// ---------------- layer-0 helpers: y0[t][f] = p[t] * rowsum(W1b)[f] ----------------
__global__ void rowsum_kernel(const float* __restrict__ W1, float* __restrict__ rs) {
    int f = threadIdx.x;
    float s = 0.f;
    for (int c = 0; c < H; ++c) s += W1[f*137 + 9 + c];
    rs[f] = s;
}
__global__ void y0_kernel(const float* __restrict__ p, const float* __restrict__ rs, float* __restrict__ Y) {
    int tid = blockIdx.x * blockDim.x + threadIdx.x;   // over T*H
    int t = tid >> 7, f = tid & 127;
    Y[tid] = p[t] * rs[f];
}

// ---------------- edge accumulation: S[t] = sum_e relu(y[t]-y[tgt] + W1a*r9 + b1) ----------------
__global__ __launch_bounds__(128) void edge_kernel(const float* __restrict__ Y, const float* __restrict__ geo,
                            const int* __restrict__ nbr, const float* __restrict__ W1,
                            const float* __restrict__ b1, float* __restrict__ S) {
    __shared__ float W1aT[9][128];
    int f = threadIdx.x;
    for (int idx = threadIdx.x; idx < 9*128; idx += 128) {
        int ff = idx / 9, c = idx % 9;
        W1aT[c][ff] = W1[ff*137 + c];
    }
    __syncthreads();
    int t = blockIdx.x;
    const float4* g4 = (const float4*)geo;
    float4 s0 = g4[t*3+0], s1 = g4[t*3+1], s2 = g4[t*3+2];
    float b1f = b1[f];
    float ysrc = Y[(size_t)t*H + f];
    float acc = 0.f;
    for (int e = 0; e < KNN_K; ++e) {
        int tg = nbr[t*KNN_K + e];
        float4 t0 = g4[tg*3+0], t1 = g4[tg*3+1], t2 = g4[tg*3+2];
        float r0 = s0.x-t0.x, r1 = s0.y-t0.y, r2 = s0.z-t0.z, r3 = s0.w-t0.w;
        float r4 = s1.x-t1.x, r5 = s1.y-t1.y, r6 = s1.z-t1.z, r7 = s1.w-t1.w;
        float r8 = s2.x-t2.x;
        float g = b1f;
        g = fmaf(W1aT[0][f], r0, g); g = fmaf(W1aT[1][f], r1, g); g = fmaf(W1aT[2][f], r2, g);
        g = fmaf(W1aT[3][f], r3, g); g = fmaf(W1aT[4][f], r4, g); g = fmaf(W1aT[5][f], r5, g);
        g = fmaf(W1aT[6][f], r6, g); g = fmaf(W1aT[7][f], r7, g); g = fmaf(W1aT[8][f], r8, g);
        float pre = g + ysrc - Y[(size_t)tg*H + f];
        acc += fmaxf(pre, 0.f);
    }
    S[(size_t)t*H + f] = acc;
}

// ---------------- dense: C[t][f] = sum_c A[t][c]*W[f][wcol0+c] + bias[f]*bscale ----------------
#define DTPB 32
__global__ __launch_bounds__(128) void dense_kernel(const float* __restrict__ A, const float* __restrict__ W,
                             int wstride, int wcol0, const float* __restrict__ bias, float bscale,
                             float* __restrict__ C) {
    __shared__ float WT[128][129];   // WT[c][f] = W[f][wcol0+c]
    __shared__ float Ar[8][128];
    int f = threadIdx.x;
    for (int r = 0; r < 128; ++r) WT[f][r] = W[r*wstride + wcol0 + f];  // thread f loads W[r][f] -> WT[f][r]
    float base = bias ? bias[f]*bscale : 0.0f;
    int t0 = blockIdx.x * DTPB;
    for (int tt = 0; tt < DTPB; tt += 8) {
        __syncthreads();
        for (int k = threadIdx.x; k < 8*128; k += 128) {
            int j = k >> 7;
            Ar[j][f] = A[(size_t)(t0+tt+j)*H + f];
        }
        __syncthreads();
        for (int j = 0; j < 8; ++j) {
            float acc = base;
            const float4* arow = (const float4*)Ar[j];
#pragma unroll
            for (int c4 = 0; c4 < 32; ++c4) {
                float4 a4 = arow[c4];
                acc = fmaf(WT[4*c4+0][f], a4.x, acc);
                acc = fmaf(WT[4*c4+1][f], a4.y, acc);
                acc = fmaf(WT[4*c4+2][f], a4.z, acc);
                acc = fmaf(WT[4*c4+3][f], a4.w, acc);
            }
            C[(size_t)(t0+tt+j)*H + f] = acc;
        }
    }
}

// ---------------- final head ----------------
__global__ void final_kernel(const float* __restrict__ X, const float* __restrict__ Wf,
                             const float* __restrict__ bf, float* __restrict__ out) {
    int t = blockIdx.x, lane = threadIdx.x;   // 64 threads
    float a = X[(size_t)t*H + lane]*Wf[lane] + X[(size_t)t*H + 64 + lane]*Wf[64+lane];
#pragma unroll
    for (int off = 32; off >= 1; off >>= 1) a += __shfl_xor(a, off);
    if (lane == 0) {
        float z = a + bf[0];
        out[t] = 1.0f / (1.0f + expf(-z));
    }
}

extern "C" void kernel_launch(void* const* d_in, const int* in_sizes, int n_in,
                              void* d_out, int out_size, void* d_ws, size_t ws_size,
                              hipStream_t stream) {
    (void)in_sizes; (void)n_in; (void)out_size; (void)ws_size;
    const float* pts   = (const float*)d_in[0];
    const int*   tris  = (const int*)d_in[1];
    const float* probs = (const float*)d_in[2];
    const float* W1[3] = {(const float*)d_in[3],  (const float*)d_in[7],  (const float*)d_in[11]};
    const float* b1[3] = {(const float*)d_in[4],  (const float*)d_in[8],  (const float*)d_in[12]};
    const float* W2[3] = {(const float*)d_in[5],  (const float*)d_in[9],  (const float*)d_in[13]};
    const float* b2[3] = {(const float*)d_in[6],  (const float*)d_in[10], (const float*)d_in[14]};
    const float* Wf = (const float*)d_in[15];
    const float* bf = (const float*)d_in[16];
    float* out = (float*)d_out;

    char* ws = (char*)d_ws;
    float*  geo = (float*)(ws + WS_GEO);
    float4* bq  = (float4*)(ws + WS_BQ);
    int*    nbr = (int*)(ws + WS_NBR);
    float*  rs  = (float*)(ws + WS_RS);
    float*  X   = (float*)(ws + WS_X);
    float*  Y   = (float*)(ws + WS_Y);
    float*  S   = (float*)(ws + WS_S);

    geom_kernel<<<(T_TRI+255)/256, 256, 0, stream>>>(pts, tris, geo, bq);
    knn_kernel<<<T_TRI/8, 512, 0, stream>>>(bq, nbr);
    rowsum_kernel<<<1, 128, 0, stream>>>(W1[0], rs);
    y0_kernel<<<(T_TRI*H)/256, 256, 0, stream>>>(probs, rs, Y);
    for (int l = 0; l < 3; ++l) {
        if (l > 0)
            dense_kernel<<<T_TRI/DTPB, 128, 0, stream>>>(X, W1[l], 137, 9, nullptr, 0.f, Y);
        edge_kernel<<<T_TRI, 128, 0, stream>>>(Y, geo, nbr, W1[l], b1[l], S);
        dense_kernel<<<T_TRI/DTPB, 128, 0, stream>>>(S, W2[l], 128, 0, b2[l], (float)KNN_K, X);
    }
    final_kernel<<<T_TRI, 64, 0, stream>>>(X, Wf, bf, out);
}

// Round 3
// 1439.332 us; speedup vs baseline: 16.1388x; 16.1388x over previous
//
#include <hip/hip_runtime.h>
#include <math.h>

#define T_TRI 20000
#define KNN_K 20
#define H     128

// ---------------- workspace layout (bytes) ----------------
#define WS_GEO   0
#define WS_BQ    (1u<<20)
#define WS_NBR   (2u<<20)
#define WS_RS    (4u<<20)
#define WS_X     (5u<<20)
#define WS_Y     (16u<<20)
#define WS_S     (27u<<20)

// ---------------- geometry ----------------
__global__ void geom_kernel(const float* __restrict__ pts, const int* __restrict__ tris,
                            float* __restrict__ geo, float4* __restrict__ bq) {
    int t = blockIdx.x * blockDim.x + threadIdx.x;
    if (t >= T_TRI) return;
    int i0 = tris[3*t], i1 = tris[3*t+1], i2 = tris[3*t+2];
    float ax = pts[3*i0], ay = pts[3*i0+1], az = pts[3*i0+2];
    float bx = pts[3*i1], by = pts[3*i1+1], bz = pts[3*i1+2];
    float cx = pts[3*i2], cy = pts[3*i2+1], cz = pts[3*i2+2];
    float e0x = ax-bx, e0y = ay-by, e0z = az-bz;   // e_ij
    float e1x = ax-cx, e1y = ay-cy, e1z = az-cz;   // e_ik
    float e2x = bx-cx, e2y = by-cy, e2z = bz-cz;   // e_jk
    float mnx = fminf(fminf(e0x,e1x),e2x), mny = fminf(fminf(e0y,e1y),e2y), mnz = fminf(fminf(e0z,e1z),e2z);
    float mxx = fmaxf(fmaxf(e0x,e1x),e2x), mxy = fmaxf(fmaxf(e0y,e1y),e2y), mxz = fmaxf(fmaxf(e0z,e1z),e2z);
    float gx = (ax+bx+cx)*(1.0f/3.0f), gy = (ay+by+cy)*(1.0f/3.0f), gz = (az+bz+cz)*(1.0f/3.0f);
    float sq = (gx*gx + gy*gy) + gz*gz;
    float* g = geo + (size_t)t*12;
    g[0]=mnx; g[1]=mny; g[2]=mnz; g[3]=mxx; g[4]=mxy; g[5]=mxz;
    g[6]=gx;  g[7]=gy;  g[8]=gz;  g[9]=0.f; g[10]=0.f; g[11]=0.f;
    bq[t] = make_float4(gx, gy, gz, sq);
}

// ---------------- knn: wave-distributed top-21, threshold + ballot ----------------
// One wave per row; current top-21 lives one entry per lane in lanes 0..20.
// Wave-uniform (theta, maxidx, maxlane) = current worst element of the set.
// Per candidate: lex-compare vs (theta,maxidx) + ballot; rare insert events
// replace the max lane's entry and recompute the max with a shfl butterfly.
// Butterfly comparator is a STRICT total order (value, idx, lane) so all
// lanes converge to identical (theta, maxidx, maxlane) even under exact ties
// (round-2 lesson: tie-divergent maxlane corrupts the set -> OOB downstream).
#define KTILE 2048
__global__ __launch_bounds__(512) void knn_kernel(const float4* __restrict__ bq, int* __restrict__ nbr) {
    __shared__ float4 tile[KTILE];
    int wave = threadIdx.x >> 6;
    int lane = threadIdx.x & 63;
    int row  = blockIdx.x * 8 + wave;
    float4 me = bq[row];

    float rd = INFINITY;              // this lane's set entry (valid for lanes 0..20)
    int   ri = 0x7FFF0000 | lane;     // distinct sentinels: total order from the start
    float theta  = INFINITY;          // wave-uniform: max (d,idx) of current set
    int   maxidx = 0x7FFFFFFF;
    int   maxlane = 20;

    for (int base = 0; base < T_TRI; base += KTILE) {
        int n = min(KTILE, T_TRI - base);
        __syncthreads();
        for (int k = threadIdx.x; k < n; k += 512) tile[k] = bq[base + k];
        __syncthreads();
        int iters = (n + 63) >> 6;
        for (int it = 0; it < iters; ++it) {
            int k = it*64 + lane;
            bool valid = (k < n);
            int kc = valid ? k : 0;
            float4 c = tile[kc];
            float dot = fmaf(me.z, c.z, fmaf(me.y, c.y, me.x*c.x));
            float d = (me.w + c.w) - 2.0f*dot;
            int j = base + k;
            if (!valid) { d = INFINITY; j = 0x7FFFFFFF; }
            bool pass = (d < theta) || (d == theta && j < maxidx);
            unsigned long long bal = __ballot(pass);
            while (bal) {
                int src = __ffsll(bal) - 1;
                bal &= bal - 1;
                float dc = __shfl(d, src);
                int   jc = __shfl(j, src);
                if ((dc < theta) || (dc == theta && jc < maxidx)) {   // re-check vs tightened theta
                    if (lane == maxlane) { rd = dc; ri = jc; }
                    // recompute wave max of (rd,ri,lane) over lanes 0..20 — strict total order
                    float bd = (lane < 21) ? rd : -INFINITY;
                    int   bi = (lane < 21) ? ri : -1;
                    int   bl = lane;
#pragma unroll
                    for (int off = 32; off >= 1; off >>= 1) {
                        float od = __shfl_xor(bd, off);
                        int   oi = __shfl_xor(bi, off);
                        int   ol = __shfl_xor(bl, off);
                        bool gt = (od > bd) || (od == bd && (oi > bi || (oi == bi && ol > bl)));
                        bd = gt ? od : bd; bi = gt ? oi : bi; bl = gt ? ol : bl;
                    }
                    theta = bd; maxidx = bi; maxlane = bl;
                }
            }
        }
    }
    // rank each kept element by counting lex-smaller peers; rank 0 = self-match, dropped
    int rank = 0;
#pragma unroll
    for (int jj = 0; jj < 21; ++jj) {
        float dj = __shfl(rd, jj);
        int   ij = __shfl(ri, jj);
        bool less = (dj < rd) || (dj == rd && ij < ri);
        rank += less ? 1 : 0;
    }
    if (lane < 21 && rank > 0) nbr[row*KNN_K + rank - 1] = ri;
}

// ---------------- layer-0 helpers: y0[t][f] = p[t] * rowsum(W1b)[f] ----------------
__global__ void rowsum_kernel(const float* __restrict__ W1, float* __restrict__ rs) {
    int f = threadIdx.x;
    float s = 0.f;
    for (int c = 0; c < H; ++c) s += W1[f*137 + 9 + c];
    rs[f] = s;
}
__global__ void y0_kernel(const float* __restrict__ p, const float* __restrict__ rs, float* __restrict__ Y) {
    int tid = blockIdx.x * blockDim.x + threadIdx.x;   // over T*H
    int t = tid >> 7, f = tid & 127;
    Y[tid] = p[t] * rs[f];
}

// ---------------- edge accumulation: S[t] = sum_e relu(y[t]-y[tgt] + W1a*r9 + b1) ----------------
__global__ __launch_bounds__(128) void edge_kernel(const float* __restrict__ Y, const float* __restrict__ geo,
                            const int* __restrict__ nbr, const float* __restrict__ W1,
                            const float* __restrict__ b1, float* __restrict__ S) {
    __shared__ float W1aT[9][128];
    int f = threadIdx.x;
    for (int idx = threadIdx.x; idx < 9*128; idx += 128) {
        int ff = idx / 9, c = idx % 9;
        W1aT[c][ff] = W1[ff*137 + c];
    }
    __syncthreads();
    int t = blockIdx.x;
    const float4* g4 = (const float4*)geo;
    float4 s0 = g4[t*3+0], s1 = g4[t*3+1], s2 = g4[t*3+2];
    float b1f = b1[f];
    float ysrc = Y[(size_t)t*H + f];
    float acc = 0.f;
    for (int e = 0; e < KNN_K; ++e) {
        int tg = nbr[t*KNN_K + e];
        float4 t0 = g4[tg*3+0], t1 = g4[tg*3+1], t2 = g4[tg*3+2];
        float r0 = s0.x-t0.x, r1 = s0.y-t0.y, r2 = s0.z-t0.z, r3 = s0.w-t0.w;
        float r4 = s1.x-t1.x, r5 = s1.y-t1.y, r6 = s1.z-t1.z, r7 = s1.w-t1.w;
        float r8 = s2.x-t2.x;
        float g = b1f;
        g = fmaf(W1aT[0][f], r0, g); g = fmaf(W1aT[1][f], r1, g); g = fmaf(W1aT[2][f], r2, g);
        g = fmaf(W1aT[3][f], r3, g); g = fmaf(W1aT[4][f], r4, g);
        g = fmaf(W1aT[5][f], r5, g); g = fmaf(W1aT[6][f], r6, g);
        g = fmaf(W1aT[7][f], r7, g); g = fmaf(W1aT[8][f], r8, g);
        float pre = g + ysrc - Y[(size_t)tg*H + f];
        acc += fmaxf(pre, 0.f);
    }
    S[(size_t)t*H + f] = acc;
}

// ---------------- dense: C[t][f] = sum_c A[t][c]*W[f][wcol0+c] + bias[f]*bscale ----------------
#define DTPB 32
__global__ __launch_bounds__(128) void dense_kernel(const float* __restrict__ A, const float* __restrict__ W,
                             int wstride, int wcol0, const float* __restrict__ bias, float bscale,
                             float* __restrict__ C) {
    __shared__ float WT[128][129];   // WT[c][f] = W[f][wcol0+c]
    __shared__ float Ar[8][128];
    int f = threadIdx.x;
    for (int r = 0; r < 128; ++r) WT[f][r] = W[r*wstride + wcol0 + f];  // thread f loads W[r][f] -> WT[f][r]
    float base = bias ? bias[f]*bscale : 0.0f;
    int t0 = blockIdx.x * DTPB;
    for (int tt = 0; tt < DTPB; tt += 8) {
        __syncthreads();
        for (int k = threadIdx.x; k < 8*128; k += 128) {
            int j = k >> 7;
            Ar[j][f] = A[(size_t)(t0+tt+j)*H + f];
        }
        __syncthreads();
        for (int j = 0; j < 8; ++j) {
            float acc = base;
            const float4* arow = (const float4*)Ar[j];
#pragma unroll
            for (int c4 = 0; c4 < 32; ++c4) {
                float4 a4 = arow[c4];
                acc = fmaf(WT[4*c4+0][f], a4.x, acc);
                acc = fmaf(WT[4*c4+1][f], a4.y, acc);
                acc = fmaf(WT[4*c4+2][f], a4.z, acc);
                acc = fmaf(WT[4*c4+3][f], a4.w, acc);
            }
            C[(size_t)(t0+tt+j)*H + f] = acc;
        }
    }
}

// ---------------- final head ----------------
__global__ void final_kernel(const float* __restrict__ X, const float* __restrict__ Wf,
                             const float* __restrict__ bf, float* __restrict__ out) {
    int t = blockIdx.x, lane = threadIdx.x;   // 64 threads
    float a = X[(size_t)t*H + lane]*Wf[lane] + X[(size_t)t*H + 64 + lane]*Wf[64+lane];
#pragma unroll
    for (int off = 32; off >= 1; off >>= 1) a += __shfl_xor(a, off);
    if (lane == 0) {
        float z = a + bf[0];
        out[t] = 1.0f / (1.0f + expf(-z));
    }
}

extern "C" void kernel_launch(void* const* d_in, const int* in_sizes, int n_in,
                              void* d_out, int out_size, void* d_ws, size_t ws_size,
                              hipStream_t stream) {
    (void)in_sizes; (void)n_in; (void)out_size; (void)ws_size;
    const float* pts   = (const float*)d_in[0];
    const int*   tris  = (const int*)d_in[1];
    const float* probs = (const float*)d_in[2];
    const float* W1[3] = {(const float*)d_in[3],  (const float*)d_in[7],  (const float*)d_in[11]};
    const float* b1[3] = {(const float*)d_in[4],  (const float*)d_in[8],  (const float*)d_in[12]};
    const float* W2[3] = {(const float*)d_in[5],  (const float*)d_in[9],  (const float*)d_in[13]};
    const float* b2[3] = {(const float*)d_in[6],  (const float*)d_in[10], (const float*)d_in[14]};
    const float* Wf = (const float*)d_in[15];
    const float* bf = (const float*)d_in[16];
    float* out = (float*)d_out;

    char* ws = (char*)d_ws;
    float*  geo = (float*)(ws + WS_GEO);
    float4* bq  = (float4*)(ws + WS_BQ);
    int*    nbr = (int*)(ws + WS_NBR);
    float*  rs  = (float*)(ws + WS_RS);
    float*  X   = (float*)(ws + WS_X);
    float*  Y   = (float*)(ws + WS_Y);
    float*  S   = (float*)(ws + WS_S);

    geom_kernel<<<(T_TRI+255)/256, 256, 0, stream>>>(pts, tris, geo, bq);
    knn_kernel<<<T_TRI/8, 512, 0, stream>>>(bq, nbr);
    rowsum_kernel<<<1, 128, 0, stream>>>(W1[0], rs);
    y0_kernel<<<(T_TRI*H)/256, 256, 0, stream>>>(probs, rs, Y);
    for (int l = 0; l < 3; ++l) {
        if (l > 0)
            dense_kernel<<<T_TRI/DTPB, 128, 0, stream>>>(X, W1[l], 137, 9, nullptr, 0.f, Y);
        edge_kernel<<<T_TRI, 128, 0, stream>>>(Y, geo, nbr, W1[l], b1[l], S);
        dense_kernel<<<T_TRI/DTPB, 128, 0, stream>>>(S, W2[l], 128, 0, b2[l], (float)KNN_K, X);
    }
    final_kernel<<<T_TRI, 64, 0, stream>>>(X, Wf, bf, out);
}

// Round 4
// 943.229 us; speedup vs baseline: 24.6272x; 1.5260x over previous
//
#include <hip/hip_runtime.h>
#include <math.h>

#define T_TRI 20000
#define KNN_K 20
#define H     128

// ---------------- workspace layout (bytes) ----------------
#define WS_GEO   0
#define WS_BQ    (1u<<20)
#define WS_NBR   (2u<<20)
#define WS_RS    (4u<<20)
#define WS_X     (5u<<20)
#define WS_Y     (16u<<20)
#define WS_S     (27u<<20)

// ---------------- geometry ----------------
__global__ void geom_kernel(const float* __restrict__ pts, const int* __restrict__ tris,
                            float* __restrict__ geo, float4* __restrict__ bq) {
    int t = blockIdx.x * blockDim.x + threadIdx.x;
    if (t >= T_TRI) return;
    int i0 = tris[3*t], i1 = tris[3*t+1], i2 = tris[3*t+2];
    float ax = pts[3*i0], ay = pts[3*i0+1], az = pts[3*i0+2];
    float bx = pts[3*i1], by = pts[3*i1+1], bz = pts[3*i1+2];
    float cx = pts[3*i2], cy = pts[3*i2+1], cz = pts[3*i2+2];
    float e0x = ax-bx, e0y = ay-by, e0z = az-bz;   // e_ij
    float e1x = ax-cx, e1y = ay-cy, e1z = az-cz;   // e_ik
    float e2x = bx-cx, e2y = by-cy, e2z = bz-cz;   // e_jk
    float mnx = fminf(fminf(e0x,e1x),e2x), mny = fminf(fminf(e0y,e1y),e2y), mnz = fminf(fminf(e0z,e1z),e2z);
    float mxx = fmaxf(fmaxf(e0x,e1x),e2x), mxy = fmaxf(fmaxf(e0y,e1y),e2y), mxz = fmaxf(fmaxf(e0z,e1z),e2z);
    float gx = (ax+bx+cx)*(1.0f/3.0f), gy = (ay+by+cy)*(1.0f/3.0f), gz = (az+bz+cz)*(1.0f/3.0f);
    float sq = (gx*gx + gy*gy) + gz*gz;
    float* g = geo + (size_t)t*12;
    g[0]=mnx; g[1]=mny; g[2]=mnz; g[3]=mxx; g[4]=mxy; g[5]=mxz;
    g[6]=gx;  g[7]=gy;  g[8]=gz;  g[9]=0.f; g[10]=0.f; g[11]=0.f;
    bq[t] = make_float4(gx, gy, gz, sq);
}

// ---------------- knn: wave-distributed SORTED top-21, threshold + ballot ----------------
// One wave per row; the top-21 set lives sorted ascending by (d,idx) across
// lanes 0..20 (lane l = rank l). Wave-uniform (theta, maxidx) = lane 20's entry.
// Per candidate: lex-compare vs (theta,maxidx) + ballot. Rare insert events:
// pos = popcount(ballot(own < new)); shift lanes pos..19 up by one (shfl_up),
// place new at lane pos, drop old max; theta/maxidx = shfl(lane 20). ~16 instr
// per event vs the old 6-round argmax butterfly (~55 instr).
// Comparator (d, idx) is a strict total order over real candidates (distinct
// idx) and distinct sentinels keep the initial set strictly sorted — no tie
// divergence possible (round-2 lesson).
// Last tile is padded with +INF candidates: theta is finite long before the
// last tile, so INF can never pass — lets the hot loop drop the bounds check.
#define KTILE 2048
__global__ __launch_bounds__(512) void knn_kernel(const float4* __restrict__ bq, int* __restrict__ nbr) {
    __shared__ float4 tile[KTILE];
    int wave = threadIdx.x >> 6;
    int lane = threadIdx.x & 63;
    int row  = blockIdx.x * 8 + wave;
    float4 me = bq[row];

    float rd = INFINITY;              // this lane's set entry (rank = lane, lanes 0..20)
    int   ri = 0x7FFF0000 | lane;     // distinct sentinels: strictly sorted from the start
    float theta  = INFINITY;          // wave-uniform: set max = lane 20's entry
    int   maxidx = 0x7FFF0014;

    for (int base = 0; base < T_TRI; base += KTILE) {
        int n = min(KTILE, T_TRI - base);
        __syncthreads();
        for (int k = threadIdx.x; k < n; k += 512) tile[k] = bq[base + k];
        for (int k = n + threadIdx.x; k < KTILE; k += 512)
            tile[k] = make_float4(INFINITY, INFINITY, INFINITY, INFINITY);
        __syncthreads();
        for (int it = 0; it < KTILE/64; ++it) {
            float4 c = tile[it*64 + lane];
            float dot = fmaf(me.z, c.z, fmaf(me.y, c.y, me.x*c.x));
            float d = (me.w + c.w) - 2.0f*dot;
            int j = base + it*64 + lane;
            bool pass = (d < theta) || (d == theta && j < maxidx);
            unsigned long long bal = __ballot(pass);
            while (bal) {
                int src = __ffsll(bal) - 1;
                bal &= bal - 1;
                float dc = __shfl(d, src);
                int   jc = __shfl(j, src);
                if ((dc < theta) || (dc == theta && jc < maxidx)) {   // re-check vs tightened theta
                    bool less = (rd < dc) || (rd == dc && ri < jc);
                    int pos = __popcll(__ballot(less) & 0x1FFFFFull);
                    float sd = __shfl_up(rd, 1);
                    int   si = __shfl_up(ri, 1);
                    if (lane < 21) {
                        if (lane == pos)      { rd = dc; ri = jc; }
                        else if (lane > pos)  { rd = sd; ri = si; }
                    }
                    theta  = __shfl(rd, 20);
                    maxidx = __shfl(ri, 20);
                }
            }
        }
    }
    // lane l holds rank-l entry; rank 0 = self, dropped (== reference idx[:,1:])
    if (lane >= 1 && lane < 21) nbr[row*KNN_K + lane - 1] = ri;
}

// ---------------- layer-0 helpers: y0[t][f] = p[t] * rowsum(W1b)[f] ----------------
__global__ void rowsum_kernel(const float* __restrict__ W1, float* __restrict__ rs) {
    int f = threadIdx.x;
    float s = 0.f;
    for (int c = 0; c < H; ++c) s += W1[f*137 + 9 + c];
    rs[f] = s;
}
__global__ void y0_kernel(const float* __restrict__ p, const float* __restrict__ rs, float* __restrict__ Y) {
    int tid = blockIdx.x * blockDim.x + threadIdx.x;   // over T*H
    int t = tid >> 7, f = tid & 127;
    Y[tid] = p[t] * rs[f];
}

// ---------------- edge accumulation: S[t] = sum_e relu(y[t]-y[tgt] + W1a*r9 + b1) ----------------
__global__ __launch_bounds__(128) void edge_kernel(const float* __restrict__ Y, const float* __restrict__ geo,
                            const int* __restrict__ nbr, const float* __restrict__ W1,
                            const float* __restrict__ b1, float* __restrict__ S) {
    __shared__ float W1aT[9][128];
    int f = threadIdx.x;
    for (int idx = threadIdx.x; idx < 9*128; idx += 128) {
        int ff = idx / 9, c = idx % 9;
        W1aT[c][ff] = W1[ff*137 + c];
    }
    __syncthreads();
    int t = blockIdx.x;
    const float4* g4 = (const float4*)geo;
    float4 s0 = g4[t*3+0], s1 = g4[t*3+1], s2 = g4[t*3+2];
    float b1f = b1[f];
    float ysrc = Y[(size_t)t*H + f];
    float acc = 0.f;
    for (int e = 0; e < KNN_K; ++e) {
        int tg = nbr[t*KNN_K + e];
        float4 t0 = g4[tg*3+0], t1 = g4[tg*3+1], t2 = g4[tg*3+2];
        float r0 = s0.x-t0.x, r1 = s0.y-t0.y, r2 = s0.z-t0.z, r3 = s0.w-t0.w;
        float r4 = s1.x-t1.x, r5 = s1.y-t1.y, r6 = s1.z-t1.z, r7 = s1.w-t1.w;
        float r8 = s2.x-t2.x;
        float g = b1f;
        g = fmaf(W1aT[0][f], r0, g); g = fmaf(W1aT[1][f], r1, g); g = fmaf(W1aT[2][f], r2, g);
        g = fmaf(W1aT[3][f], r3, g); g = fmaf(W1aT[4][f], r4, g);
        g = fmaf(W1aT[5][f], r5, g); g = fmaf(W1aT[6][f], r6, g);
        g = fmaf(W1aT[7][f], r7, g); g = fmaf(W1aT[8][f], r8, g);
        float pre = g + ysrc - Y[(size_t)tg*H + f];
        acc += fmaxf(pre, 0.f);
    }
    S[(size_t)t*H + f] = acc;
}

// ---------------- dense: C[t][f] = sum_c A[t][c]*W[f][wcol0+c] + bias[f]*bscale ----------------
#define DTPB 32
__global__ __launch_bounds__(128) void dense_kernel(const float* __restrict__ A, const float* __restrict__ W,
                             int wstride, int wcol0, const float* __restrict__ bias, float bscale,
                             float* __restrict__ C) {
    __shared__ float WT[128][129];   // WT[c][f] = W[f][wcol0+c]
    __shared__ float Ar[8][128];
    int f = threadIdx.x;
    for (int r = 0; r < 128; ++r) WT[f][r] = W[r*wstride + wcol0 + f];  // thread f loads W[r][f] -> WT[f][r]
    float base = bias ? bias[f]*bscale : 0.0f;
    int t0 = blockIdx.x * DTPB;
    for (int tt = 0; tt < DTPB; tt += 8) {
        __syncthreads();
        for (int k = threadIdx.x; k < 8*128; k += 128) {
            int j = k >> 7;
            Ar[j][f] = A[(size_t)(t0+tt+j)*H + f];
        }
        __syncthreads();
        for (int j = 0; j < 8; ++j) {
            float acc = base;
            const float4* arow = (const float4*)Ar[j];
#pragma unroll
            for (int c4 = 0; c4 < 32; ++c4) {
                float4 a4 = arow[c4];
                acc = fmaf(WT[4*c4+0][f], a4.x, acc);
                acc = fmaf(WT[4*c4+1][f], a4.y, acc);
                acc = fmaf(WT[4*c4+2][f], a4.z, acc);
                acc = fmaf(WT[4*c4+3][f], a4.w, acc);
            }
            C[(size_t)(t0+tt+j)*H + f] = acc;
        }
    }
}

// ---------------- final head ----------------
__global__ void final_kernel(const float* __restrict__ X, const float* __restrict__ Wf,
                             const float* __restrict__ bf, float* __restrict__ out) {
    int t = blockIdx.x, lane = threadIdx.x;   // 64 threads
    float a = X[(size_t)t*H + lane]*Wf[lane] + X[(size_t)t*H + 64 + lane]*Wf[64+lane];
#pragma unroll
    for (int off = 32; off >= 1; off >>= 1) a += __shfl_xor(a, off);
    if (lane == 0) {
        float z = a + bf[0];
        out[t] = 1.0f / (1.0f + expf(-z));
    }
}

extern "C" void kernel_launch(void* const* d_in, const int* in_sizes, int n_in,
                              void* d_out, int out_size, void* d_ws, size_t ws_size,
                              hipStream_t stream) {
    (void)in_sizes; (void)n_in; (void)out_size; (void)ws_size;
    const float* pts   = (const float*)d_in[0];
    const int*   tris  = (const int*)d_in[1];
    const float* probs = (const float*)d_in[2];
    const float* W1[3] = {(const float*)d_in[3],  (const float*)d_in[7],  (const float*)d_in[11]};
    const float* b1[3] = {(const float*)d_in[4],  (const float*)d_in[8],  (const float*)d_in[12]};
    const float* W2[3] = {(const float*)d_in[5],  (const float*)d_in[9],  (const float*)d_in[13]};
    const float* b2[3] = {(const float*)d_in[6],  (const float*)d_in[10], (const float*)d_in[14]};
    const float* Wf = (const float*)d_in[15];
    const float* bf = (const float*)d_in[16];
    float* out = (float*)d_out;

    char* ws = (char*)d_ws;
    float*  geo = (float*)(ws + WS_GEO);
    float4* bq  = (float4*)(ws + WS_BQ);
    int*    nbr = (int*)(ws + WS_NBR);
    float*  rs  = (float*)(ws + WS_RS);
    float*  X   = (float*)(ws + WS_X);
    float*  Y   = (float*)(ws + WS_Y);
    float*  S   = (float*)(ws + WS_S);

    geom_kernel<<<(T_TRI+255)/256, 256, 0, stream>>>(pts, tris, geo, bq);
    knn_kernel<<<T_TRI/8, 512, 0, stream>>>(bq, nbr);
    rowsum_kernel<<<1, 128, 0, stream>>>(W1[0], rs);
    y0_kernel<<<(T_TRI*H)/256, 256, 0, stream>>>(probs, rs, Y);
    for (int l = 0; l < 3; ++l) {
        if (l > 0)
            dense_kernel<<<T_TRI/DTPB, 128, 0, stream>>>(X, W1[l], 137, 9, nullptr, 0.f, Y);
        edge_kernel<<<T_TRI, 128, 0, stream>>>(Y, geo, nbr, W1[l], b1[l], S);
        dense_kernel<<<T_TRI/DTPB, 128, 0, stream>>>(S, W2[l], 128, 0, b2[l], (float)KNN_K, X);
    }
    final_kernel<<<T_TRI, 64, 0, stream>>>(X, Wf, bf, out);
}